// Round 2
// baseline (1154.233 us; speedup 1.0000x reference)
//
#include <hip/hip_runtime.h>
#include <hip/hip_bf16.h>

typedef unsigned short ushort;
typedef __attribute__((ext_vector_type(4))) float floatx4;
typedef __attribute__((ext_vector_type(8))) short short8;

constexpr int NB   = 512;
constexpr int T    = 43;
constexpr int H    = 128;
constexpr int NT   = NB * T;       // 22016
constexpr int DK   = 96;
constexpr int DFF  = 2048;
constexpr int OUTD = 8000;

__device__ __forceinline__ ushort f2b(float f) {
    __hip_bfloat16 h = __float2bfloat16(f);
    return *reinterpret_cast<ushort*>(&h);
}

#define GLOAD16(g, l) __builtin_amdgcn_global_load_lds( \
    (const __attribute__((address_space(1))) unsigned int*)(g), \
    (__attribute__((address_space(3))) unsigned int*)(l), 16, 0, 0)

// ---------------------------------------------------------------------------
// gemm_bt: C[M,N] = A[M,K](bf16) @ B[Npad,K](bf16)^T + bias (generic K%32==0)
// Double-buffered LDS: one barrier per k-step, next-step loads in flight
// during current step's MFMAs. Used for proj (K=192) and FFN2 (K=2048),
// which run at ~1 block/CU (grid (1,172)) and are latency-exposed.
// ---------------------------------------------------------------------------
template<bool RELU, bool OUT_BF16>
__global__ __launch_bounds__(256) void gemm_bt(
    const ushort* __restrict__ A, const ushort* __restrict__ B,
    const float* __restrict__ bias, void* __restrict__ Cv,
    int M, int N, int K)
{
    __shared__ ushort As[2][128 * 32];
    __shared__ ushort Bs[2][128 * 32];
    const int tid  = threadIdx.x;
    const int lane = tid & 63;
    const int wm   = (tid >> 6) & 1;
    const int wn   = (tid >> 6) >> 1;
    const long tileM = (long)blockIdx.y * 128;
    const long tileN = (long)blockIdx.x * 128;

    floatx4 acc[4][4] = {};

    const ushort* ga0 = A + (tileM + (tid >> 2)) * (long)K + (tid & 3) * 8;
    const ushort* ga1 = A + (tileM + 64 + (tid >> 2)) * (long)K + (tid & 3) * 8;
    const ushort* gb0 = B + (tileN + (tid >> 2)) * (long)K + (tid & 3) * 8;
    const ushort* gb1 = B + (tileN + 64 + (tid >> 2)) * (long)K + (tid & 3) * 8;

#define STAGE_BT(buf, k0) do { \
        GLOAD16(ga0 + (k0), &As[buf][tid * 8]); \
        GLOAD16(ga1 + (k0), &As[buf][(tid + 256) * 8]); \
        GLOAD16(gb0 + (k0), &Bs[buf][tid * 8]); \
        GLOAD16(gb1 + (k0), &Bs[buf][(tid + 256) * 8]); } while (0)

    const int nsteps = K >> 5;
    STAGE_BT(0, 0);
    int cur = 0;
    for (int t = 0; t < nsteps; ++t) {
        __syncthreads();                      // drains vmcnt: buf 'cur' ready
        if (t + 1 < nsteps) STAGE_BT(cur ^ 1, (t + 1) * 32);
        short8 af[4], bfr[4];
        #pragma unroll
        for (int mi = 0; mi < 4; ++mi)
            af[mi] = *(const short8*)&As[cur][(wm * 64 + mi * 16 + (lane & 15)) * 32 + (lane >> 4) * 8];
        #pragma unroll
        for (int ni = 0; ni < 4; ++ni)
            bfr[ni] = *(const short8*)&Bs[cur][(wn * 64 + ni * 16 + (lane & 15)) * 32 + (lane >> 4) * 8];
        #pragma unroll
        for (int mi = 0; mi < 4; ++mi)
            #pragma unroll
            for (int ni = 0; ni < 4; ++ni)
                acc[mi][ni] = __builtin_amdgcn_mfma_f32_16x16x32_bf16(
                    af[mi], bfr[ni], acc[mi][ni], 0, 0, 0);
        cur ^= 1;
    }
#undef STAGE_BT

    const int r0 = wm * 64 + (lane >> 4) * 4;
    const int c0 = wn * 64 + (lane & 15);
    #pragma unroll
    for (int ni = 0; ni < 4; ++ni) {
        long col = tileN + c0 + ni * 16;
        if (col < N) {
            float bv = bias ? bias[col] : 0.0f;
            #pragma unroll
            for (int mi = 0; mi < 4; ++mi) {
                #pragma unroll
                for (int r = 0; r < 4; ++r) {
                    long row = tileM + r0 + mi * 16 + r;
                    float v = acc[mi][ni][r] + bv;
                    if (RELU) v = v > 0.0f ? v : 0.0f;
                    if (OUT_BF16) ((ushort*)Cv)[row * N + col] = f2b(v);
                    else          ((float*)Cv)[row * N + col] = v;
                }
            }
        }
    }
}

// ---------------------------------------------------------------------------
// gemm_k128: K==128 specialization. A-tile [128,128] staged ONCE per block
// (XOR-swizzled via pre-swizzled global source, linear LDS dest per m104/m173),
// A-fragments held in registers across an N-tile loop (NTPB tiles of 128 cols).
// Per N-tile: 2 barriers total (vs 8 in the generic 4-kstep path).
// Swizzle: within each 256B row, byte ^= ((row&7)<<4) -> frag ds_read_b128
// goes from 8/16-way bank conflict to 2-way (free).
// NTS: non-temporal stores for stream-out (C never re-read / read-once) so
// the 704MB/90MB/50MB write streams don't evict A/B tiles from L2.
// ---------------------------------------------------------------------------
template<int NTPB, bool RELU, bool OUT_BF16, bool NTS>
__global__ __launch_bounds__(256, 2) void gemm_k128(
    const ushort* __restrict__ A, const ushort* __restrict__ B,
    const float* __restrict__ bias, void* __restrict__ Cv, int N)
{
    __shared__ ushort As[128 * 128];   // 32 KB
    __shared__ ushort Bs[128 * 128];   // 32 KB  (total 64KB -> 2 blocks/CU)
    const int tid  = threadIdx.x;
    const int lane = tid & 63;
    const int wm   = (tid >> 6) & 1;
    const int wn   = (tid >> 7);
    const long tileM  = (long)blockIdx.y * 128;
    const long tileN0 = (long)blockIdx.x * (NTPB * 128);

    // ---- stage A once: chunk idx = c*256+tid; row=idx>>4; 16B sub-chunk
    // source column XOR-swizzled, LDS dest linear (lane*16 discipline kept)
    #pragma unroll
    for (int c = 0; c < 8; ++c) {
        int idx = c * 256 + tid;
        int row = idx >> 4;
        int sw  = ((idx & 15) * 16) ^ ((row & 7) << 4);
        const char* src = (const char*)A + (tileM + row) * 256 + sw;
        GLOAD16(src, &As[idx * 8]);
    }
    __syncthreads();

    // ---- A fragments to registers: af[mi][kk], row = lane&15, k = kk*32+(lane>>4)*8
    short8 af[4][4];
    const int seg16 = (lane >> 4) * 16;
    #pragma unroll
    for (int mi = 0; mi < 4; ++mi) {
        int r  = wm * 64 + mi * 16 + (lane & 15);
        int xr = (r & 7) << 4;
        #pragma unroll
        for (int kk = 0; kk < 4; ++kk)
            af[mi][kk] = *(const short8*)((const char*)As + r * 256 + ((kk * 64 + seg16) ^ xr));
    }

    for (int j = 0; j < NTPB; ++j) {
        const long tileN = tileN0 + j * 128;
        __syncthreads();                 // prior tile's B-frag reads done
        #pragma unroll
        for (int c = 0; c < 8; ++c) {
            int idx = c * 256 + tid;
            int row = idx >> 4;
            int sw  = ((idx & 15) * 16) ^ ((row & 7) << 4);
            const char* src = (const char*)B + (tileN + row) * 256 + sw;
            GLOAD16(src, &Bs[idx * 8]);
        }
        __syncthreads();                 // B tile ready (vmcnt drained)

        floatx4 acc[4][4] = {};
        #pragma unroll
        for (int kk = 0; kk < 4; ++kk) {
            short8 bfr[4];
            #pragma unroll
            for (int ni = 0; ni < 4; ++ni) {
                int r  = wn * 64 + ni * 16 + (lane & 15);
                int xr = (r & 7) << 4;
                bfr[ni] = *(const short8*)((const char*)Bs + r * 256 + ((kk * 64 + seg16) ^ xr));
            }
            #pragma unroll
            for (int mi = 0; mi < 4; ++mi)
                #pragma unroll
                for (int ni = 0; ni < 4; ++ni)
                    acc[mi][ni] = __builtin_amdgcn_mfma_f32_16x16x32_bf16(
                        af[mi][kk], bfr[ni], acc[mi][ni], 0, 0, 0);
        }

        const int r0 = wm * 64 + (lane >> 4) * 4;
        const int c0 = wn * 64 + (lane & 15);
        #pragma unroll
        for (int ni = 0; ni < 4; ++ni) {
            long col = tileN + c0 + ni * 16;
            if (col < N) {
                float bv = bias ? bias[col] : 0.0f;
                #pragma unroll
                for (int mi = 0; mi < 4; ++mi) {
                    #pragma unroll
                    for (int r = 0; r < 4; ++r) {
                        long row = tileM + r0 + mi * 16 + r;
                        float v = acc[mi][ni][r] + bv;
                        if (RELU) v = v > 0.0f ? v : 0.0f;
                        if (OUT_BF16) {
                            ushort hv = f2b(v);
                            ushort* p = (ushort*)Cv + row * N + col;
                            if (NTS) __builtin_nontemporal_store(hv, p); else *p = hv;
                        } else {
                            float* p = (float*)Cv + row * N + col;
                            if (NTS) __builtin_nontemporal_store(v, p); else *p = v;
                        }
                    }
                }
            }
        }
    }
}

// ---------------------------------------------------------------------------
// embed: x = emb[inputs] + pos_emb  (fp32 + bf16 copies)
// ---------------------------------------------------------------------------
__global__ __launch_bounds__(256) void embed_kernel(
    const int* __restrict__ inputs, const float* __restrict__ emb,
    const float* __restrict__ pos, float* __restrict__ xf, ushort* __restrict__ xb)
{
    long i = (long)blockIdx.x * 256 + threadIdx.x;   // over NT*H
    int h  = (int)(i & 127);
    int nt = (int)(i >> 7);
    int t  = nt % T;
    float v = emb[(long)inputs[nt] * H + h] + pos[t * H + h];
    xf[i] = v;
    xb[i] = f2b(v);
}

// ---------------------------------------------------------------------------
// pack 6 qkv weights [96,128] -> [640,128] bf16 (zero pad), biases -> [640]
// ---------------------------------------------------------------------------
__global__ __launch_bounds__(256) void pack_qkv(
    const float* q1, const float* k1, const float* v1,
    const float* q2, const float* k2, const float* v2,
    const float* bq1, const float* bk1, const float* bv1,
    const float* bq2, const float* bk2, const float* bv2,
    ushort* __restrict__ W, float* __restrict__ bias)
{
    int i = blockIdx.x * 256 + threadIdx.x;   // 640*128
    int n = i >> 7, kk = i & 127;
    float val = 0.0f;
    if (n < 576) {
        const float* ws[6] = {q1, k1, v1, q2, k2, v2};
        val = ws[n / 96][(n % 96) * 128 + kk];
    }
    W[i] = f2b(val);
    if (kk == 0) {
        float bv = 0.0f;
        if (n < 576) {
            const float* bs[6] = {bq1, bk1, bv1, bq2, bk2, bv2};
            bv = bs[n / 96][n % 96];
        }
        bias[n] = bv;
    }
}

// ---------------------------------------------------------------------------
// all 4 fp32->bf16 weight conversions in ONE launch (block-range dispatch)
// ranges: [0,96) Wproj 128x192 | [96,1120) Wff1 2048x128 |
//         [1120,2144) Wff2 128x2048 | [2144,6176) Wfin 8000x128 pad->8064
// ---------------------------------------------------------------------------
__global__ __launch_bounds__(256) void cvt_all(
    const float* __restrict__ Wproj, const float* __restrict__ Wff1,
    const float* __restrict__ Wff2,  const float* __restrict__ Wfin,
    ushort* __restrict__ Wp_b, ushort* __restrict__ W1_b,
    ushort* __restrict__ W2_b, ushort* __restrict__ Wf_b)
{
    const int b = blockIdx.x, tid = threadIdx.x;
    if (b < 96) {
        int i = b * 256 + tid;                 // 128*192
        Wp_b[i] = f2b(Wproj[i]);
    } else if (b < 1120) {
        int i = (b - 96) * 256 + tid;          // 2048*128
        W1_b[i] = f2b(Wff1[i]);
    } else if (b < 2144) {
        int i = (b - 1120) * 256 + tid;        // 128*2048
        W2_b[i] = f2b(Wff2[i]);
    } else {
        long i = (long)(b - 2144) * 256 + tid; // 8064*128
        long r = i >> 7;
        Wf_b[i] = f2b(r < OUTD ? Wfin[i] : 0.0f);
    }
}

// ---------------------------------------------------------------------------
// attention: one block per (head, batch). qkv fp32 [NT,576] layout
// [q1 k1 v1 q2 k2 v2] (96 each). writes h12 bf16 [NT,192].
// ---------------------------------------------------------------------------
__global__ __launch_bounds__(256) void attn_kernel(
    const float* __restrict__ qkv, ushort* __restrict__ h12)
{
    const int head = blockIdx.x;
    const int n    = blockIdx.y;
    const int tid  = threadIdx.x;
    __shared__ float q[T][DK], k[T][DK], v[T][DK];
    __shared__ float s[T][T + 1];
    const float scale = 0.10206207261596575f;   // 1/sqrt(96)
    const long base = (long)n * T * 576 + head * 288;

    for (int i = tid; i < T * DK; i += 256) {
        int r = i / DK, c = i % DK;
        q[r][c] = qkv[base + r * 576 + c];
        k[r][c] = qkv[base + r * 576 + 96 + c];
        v[r][c] = qkv[base + r * 576 + 192 + c];
    }
    __syncthreads();
    for (int i = tid; i < T * T; i += 256) {
        int r = i / T, c = i % T;
        float d = 0.0f;
        #pragma unroll 8
        for (int x = 0; x < DK; ++x) d += q[r][x] * k[c][x];
        s[r][c] = d * scale;
    }
    __syncthreads();
    if (tid < T) {
        float mx = -1e30f;
        for (int j = 0; j < T; ++j) mx = fmaxf(mx, s[tid][j]);
        float sum = 0.0f;
        for (int j = 0; j < T; ++j) { float e = __expf(s[tid][j] - mx); s[tid][j] = e; sum += e; }
        float inv = 1.0f / sum;
        for (int j = 0; j < T; ++j) s[tid][j] *= inv;
    }
    __syncthreads();
    for (int i = tid; i < T * DK; i += 256) {
        int r = i / DK, c = i % DK;
        float d = 0.0f;
        #pragma unroll
        for (int j = 0; j < T; ++j) d += s[r][j] * v[j][c];
        h12[((long)n * T + r) * 192 + head * 96 + c] = f2b(d);
    }
}

// ---------------------------------------------------------------------------
// residual + LayerNorm, wave per row (H=128, 2 elems/lane)
// ---------------------------------------------------------------------------
__global__ __launch_bounds__(256) void ln_kernel(
    const float* __restrict__ a, const float* __restrict__ resid,
    const float* __restrict__ g, const float* __restrict__ b,
    ushort* __restrict__ out_bf, float* __restrict__ out_f32, int M)
{
    const int lane = threadIdx.x & 63;
    const int row  = blockIdx.x * 4 + (threadIdx.x >> 6);
    if (row >= M) return;
    const long o = (long)row * H;
    float v0 = a[o + lane] + resid[o + lane];
    float v1 = a[o + 64 + lane] + resid[o + 64 + lane];
    float s  = v0 + v1, sq = v0 * v0 + v1 * v1;
    #pragma unroll
    for (int w = 32; w; w >>= 1) { s += __shfl_xor(s, w, 64); sq += __shfl_xor(sq, w, 64); }
    float mean = s * (1.0f / H);
    float var  = sq * (1.0f / H) - mean * mean;
    float rstd = rsqrtf(var + 1e-5f);
    float o0 = (v0 - mean) * rstd * g[lane] + b[lane];
    float o1 = (v1 - mean) * rstd * g[64 + lane] + b[64 + lane];
    out_bf[o + lane] = f2b(o0);
    out_bf[o + 64 + lane] = f2b(o1);
    if (out_f32) { out_f32[o + lane] = o0; out_f32[o + 64 + lane] = o1; }
}

// ---------------------------------------------------------------------------
extern "C" void kernel_launch(void* const* d_in, const int* in_sizes, int n_in,
                              void* d_out, int out_size, void* d_ws, size_t ws_size,
                              hipStream_t stream)
{
    const int*   inputs  = (const int*)  d_in[0];
    const float* emb     = (const float*)d_in[1];
    const float* pos_emb = (const float*)d_in[2];
    const float* Wk1 = (const float*)d_in[3],  *bk1 = (const float*)d_in[4];
    const float* Wv1 = (const float*)d_in[5],  *bv1 = (const float*)d_in[6];
    const float* Wq1 = (const float*)d_in[7],  *bq1 = (const float*)d_in[8];
    const float* Wk2 = (const float*)d_in[9],  *bk2 = (const float*)d_in[10];
    const float* Wv2 = (const float*)d_in[11], *bv2 = (const float*)d_in[12];
    const float* Wq2 = (const float*)d_in[13], *bq2 = (const float*)d_in[14];
    const float* Wproj = (const float*)d_in[15], *bproj = (const float*)d_in[16];
    const float* g_mh  = (const float*)d_in[17], *b_mh  = (const float*)d_in[18];
    const float* Wff1  = (const float*)d_in[19], *bff1  = (const float*)d_in[20];
    const float* Wff2  = (const float*)d_in[21], *bff2  = (const float*)d_in[22];
    const float* g_ff  = (const float*)d_in[23], *b_ff  = (const float*)d_in[24];
    const float* Wfin  = (const float*)d_in[25], *bfin  = (const float*)d_in[26];

    // --- Scratch placement: dead-before-final-gemm buffers live in d_out ---
    char* scr = (char*)d_out;
    size_t soff = 0;
    auto salloc = [&](size_t bytes) {
        void* p = scr + soff;
        soff = (soff + bytes + 255) & ~(size_t)255;
        return p;
    };
    float*  x_f   = (float*) salloc((size_t)NT * H * 4);
    ushort* x_b   = (ushort*)salloc((size_t)NT * H * 2);
    float*  qkv   = (float*) salloc((size_t)NT * 576 * 4);
    ushort* h12   = (ushort*)salloc((size_t)NT * 192 * 2);
    float*  mh    = (float*) salloc((size_t)NT * H * 4);
    float*  xln_f = (float*) salloc((size_t)NT * H * 4);
    ushort* xln_b = (ushort*)salloc((size_t)NT * H * 2);
    ushort* ffa   = (ushort*)salloc((size_t)NT * DFF * 2);
    float*  ff2   = (float*) salloc((size_t)NT * H * 4);
    ushort* Wqkv  = (ushort*)salloc(640 * 128 * 2);
    float*  bqkv  = (float*) salloc(640 * 4);
    ushort* Wp_b  = (ushort*)salloc(128 * 192 * 2);
    ushort* W1_b  = (ushort*)salloc((size_t)DFF * 128 * 2);
    ushort* W2_b  = (ushort*)salloc((size_t)128 * DFF * 2);

    char* ws = (char*)d_ws;
    size_t woff = 0;
    auto walloc = [&](size_t bytes) {
        void* p = ws + woff;
        woff = (woff + bytes + 255) & ~(size_t)255;
        return p;
    };
    ushort* y_b  = (ushort*)walloc((size_t)NT * H * 2);      // 5.6 MB
    ushort* Wf_b = (ushort*)walloc((size_t)8064 * 128 * 2);  // 2.1 MB

    // weight conversion / packing (2 launches instead of 5)
    pack_qkv<<<(640 * 128) / 256, 256, 0, stream>>>(
        Wq1, Wk1, Wv1, Wq2, Wk2, Wv2, bq1, bk1, bv1, bq2, bk2, bv2, Wqkv, bqkv);
    cvt_all<<<6176, 256, 0, stream>>>(Wproj, Wff1, Wff2, Wfin, Wp_b, W1_b, W2_b, Wf_b);

    // embed
    embed_kernel<<<(NT * H) / 256, 256, 0, stream>>>(inputs, emb, pos_emb, x_f, x_b);

    const int MT = NT / 128;   // 172 M-tiles

    // QKV projection: [NT,128] @ [640,128]^T -> [NT,576] fp32 (nt stream-out)
    gemm_k128<1, false, false, true><<<dim3(5, MT), 256, 0, stream>>>(
        x_b, Wqkv, bqkv, qkv, 576);

    // attention -> h12 bf16 [NT,192]
    attn_kernel<<<dim3(2, NB), 256, 0, stream>>>(qkv, h12);

    // Wproj: [NT,192] @ [128,192]^T -> mh fp32 [NT,128] (read right after: keep cached)
    gemm_bt<false, false><<<dim3(1, MT), 256, 0, stream>>>(h12, Wp_b, bproj, mh, NT, 128, 192);

    // LN1: xln = LN(mh + x)
    ln_kernel<<<NT / 4, 256, 0, stream>>>(mh, x_f, g_mh, b_mh, xln_b, xln_f, NT);

    // FFN1 + relu -> bf16 [NT,2048] (90MB, nt stream-out)
    gemm_k128<4, true, true, true><<<dim3(4, MT), 256, 0, stream>>>(
        xln_b, W1_b, bff1, ffa, DFF);

    // FFN2 -> fp32 [NT,128]
    gemm_bt<false, false><<<dim3(1, MT), 256, 0, stream>>>(ffa, W2_b, bff2, ff2, NT, 128, DFF);

    // LN2: y = LN(ff2 + xln)
    ln_kernel<<<NT / 4, 256, 0, stream>>>(ff2, xln_f, g_ff, b_ff, y_b, nullptr, NT);

    // final: [NT,128] @ [8064,128]^T -> d_out fp32 [NT,8000] (704MB nt stream-out)
    gemm_k128<9, false, false, true><<<dim3(7, MT), 256, 0, stream>>>(
        y_b, Wf_b, bfin, (float*)d_out, OUTD);
}

// Round 3
// 1033.239 us; speedup vs baseline: 1.1171x; 1.1171x over previous
//
#include <hip/hip_runtime.h>
#include <hip/hip_bf16.h>

typedef unsigned short ushort;
typedef __attribute__((ext_vector_type(4))) float floatx4;
typedef __attribute__((ext_vector_type(8))) short short8;

constexpr int NB   = 512;
constexpr int T    = 43;
constexpr int H    = 128;
constexpr int NT   = NB * T;       // 22016
constexpr int DK   = 96;
constexpr int DFF  = 2048;
constexpr int OUTD = 8000;

__device__ __forceinline__ ushort f2b(float f) {
    __hip_bfloat16 h = __float2bfloat16(f);
    return *reinterpret_cast<ushort*>(&h);
}

#define GLOAD16(g, l) __builtin_amdgcn_global_load_lds( \
    (const __attribute__((address_space(1))) unsigned int*)(g), \
    (__attribute__((address_space(3))) unsigned int*)(l), 16, 0, 0)

// ---------------------------------------------------------------------------
// GEMM: C[M,N] = A[M,K](bf16) @ B[Npad,K](bf16)^T + bias ; optional relu/bf16.
// Baseline single-buffer structure (16KB LDS, ~3-4 blocks/CU): these small-K
// GEMMs are latency-hidden by TLP across co-resident blocks — round-0's
// bigger-LDS variants cut occupancy and regressed (+92us). Do not re-add.
// NTS: non-temporal C store — ONLY for the final 704MB stream (never re-read),
// keeps y_b/Wf_b L2-resident. Never use NTS on a buffer a later kernel reads.
// ---------------------------------------------------------------------------
template<bool RELU, bool OUT_BF16, bool NTS>
__global__ __launch_bounds__(256) void gemm_bt(
    const ushort* __restrict__ A, const ushort* __restrict__ B,
    const float* __restrict__ bias, void* __restrict__ Cv,
    int M, int N, int K)
{
    __shared__ ushort As[128 * 32];
    __shared__ ushort Bs[128 * 32];
    const int tid  = threadIdx.x;
    const int lane = tid & 63;
    const int wm   = (tid >> 6) & 1;
    const int wn   = (tid >> 6) >> 1;
    const long tileM = (long)blockIdx.y * 128;
    const long tileN = (long)blockIdx.x * 128;

    floatx4 acc[4][4] = {};

    const ushort* ga0 = A + (tileM + (tid >> 2)) * (long)K + (tid & 3) * 8;
    const ushort* ga1 = A + (tileM + 64 + (tid >> 2)) * (long)K + (tid & 3) * 8;
    const ushort* gb0 = B + (tileN + (tid >> 2)) * (long)K + (tid & 3) * 8;
    const ushort* gb1 = B + (tileN + 64 + (tid >> 2)) * (long)K + (tid & 3) * 8;

    for (int k0 = 0; k0 < K; k0 += 32) {
        __syncthreads();
        GLOAD16(ga0 + k0, &As[tid * 8]);
        GLOAD16(ga1 + k0, &As[(tid + 256) * 8]);
        GLOAD16(gb0 + k0, &Bs[tid * 8]);
        GLOAD16(gb1 + k0, &Bs[(tid + 256) * 8]);
        __syncthreads();
        short8 af[4], bfr[4];
        #pragma unroll
        for (int mi = 0; mi < 4; ++mi)
            af[mi] = *(const short8*)&As[(wm * 64 + mi * 16 + (lane & 15)) * 32 + (lane >> 4) * 8];
        #pragma unroll
        for (int ni = 0; ni < 4; ++ni)
            bfr[ni] = *(const short8*)&Bs[(wn * 64 + ni * 16 + (lane & 15)) * 32 + (lane >> 4) * 8];
        #pragma unroll
        for (int mi = 0; mi < 4; ++mi)
            #pragma unroll
            for (int ni = 0; ni < 4; ++ni)
                acc[mi][ni] = __builtin_amdgcn_mfma_f32_16x16x32_bf16(
                    af[mi], bfr[ni], acc[mi][ni], 0, 0, 0);
    }

    const int r0 = wm * 64 + (lane >> 4) * 4;
    const int c0 = wn * 64 + (lane & 15);
    #pragma unroll
    for (int ni = 0; ni < 4; ++ni) {
        long col = tileN + c0 + ni * 16;
        if (col < N) {
            float bv = bias ? bias[col] : 0.0f;
            #pragma unroll
            for (int mi = 0; mi < 4; ++mi) {
                #pragma unroll
                for (int r = 0; r < 4; ++r) {
                    long row = tileM + r0 + mi * 16 + r;
                    float v = acc[mi][ni][r] + bv;
                    if (RELU) v = v > 0.0f ? v : 0.0f;
                    if (OUT_BF16) {
                        ushort hv = f2b(v);
                        ushort* p = (ushort*)Cv + row * N + col;
                        if (NTS) __builtin_nontemporal_store(hv, p); else *p = hv;
                    } else {
                        float* p = (float*)Cv + row * N + col;
                        if (NTS) __builtin_nontemporal_store(v, p); else *p = v;
                    }
                }
            }
        }
    }
}

// ---------------------------------------------------------------------------
// gemm_ln: C = A @ B^T + bias, then out = LN(C + resid) fused in the epilogue.
// N fixed = 128 (one block covers full rows -> in-block row statistics).
// Row sums: in-lane over ni, shfl_xor over lane&15 (col group), then a 2-entry
// LDS exchange across the two wn wave-halves (overlaid on dead As buffer).
// Replaces {gemm -> fp32 buffer -> ln_kernel} : -2 launches, -44MB traffic.
// ---------------------------------------------------------------------------
template<bool WRITE_F32>
__global__ __launch_bounds__(256) void gemm_ln(
    const ushort* __restrict__ A, const ushort* __restrict__ B,
    const float* __restrict__ bias, const float* __restrict__ resid,
    const float* __restrict__ g, const float* __restrict__ bvec,
    ushort* __restrict__ out_bf, float* __restrict__ out_f32, int K)
{
    __shared__ ushort As[128 * 32];
    __shared__ ushort Bs[128 * 32];
    const int tid  = threadIdx.x;
    const int lane = tid & 63;
    const int wm   = (tid >> 6) & 1;
    const int wn   = (tid >> 6) >> 1;
    const long tileM = (long)blockIdx.x * 128;

    floatx4 acc[4][4] = {};

    const ushort* ga0 = A + (tileM + (tid >> 2)) * (long)K + (tid & 3) * 8;
    const ushort* ga1 = A + (tileM + 64 + (tid >> 2)) * (long)K + (tid & 3) * 8;
    const ushort* gb0 = B + ((tid >> 2)) * (long)K + (tid & 3) * 8;
    const ushort* gb1 = B + (64 + (tid >> 2)) * (long)K + (tid & 3) * 8;

    for (int k0 = 0; k0 < K; k0 += 32) {
        __syncthreads();
        GLOAD16(ga0 + k0, &As[tid * 8]);
        GLOAD16(ga1 + k0, &As[(tid + 256) * 8]);
        GLOAD16(gb0 + k0, &Bs[tid * 8]);
        GLOAD16(gb1 + k0, &Bs[(tid + 256) * 8]);
        __syncthreads();
        short8 af[4], bfr[4];
        #pragma unroll
        for (int mi = 0; mi < 4; ++mi)
            af[mi] = *(const short8*)&As[(wm * 64 + mi * 16 + (lane & 15)) * 32 + (lane >> 4) * 8];
        #pragma unroll
        for (int ni = 0; ni < 4; ++ni)
            bfr[ni] = *(const short8*)&Bs[(wn * 64 + ni * 16 + (lane & 15)) * 32 + (lane >> 4) * 8];
        #pragma unroll
        for (int mi = 0; mi < 4; ++mi)
            #pragma unroll
            for (int ni = 0; ni < 4; ++ni)
                acc[mi][ni] = __builtin_amdgcn_mfma_f32_16x16x32_bf16(
                    af[mi], bfr[ni], acc[mi][ni], 0, 0, 0);
    }

    // ---- epilogue: vals = acc + bias + resid; per-row mean/var; normalize
    const int r0 = wm * 64 + (lane >> 4) * 4;
    const int c0 = wn * 64 + (lane & 15);
    float vals[4][4][4];
    float rs[4][4] = {};   // per-(mi,r) partial sums over this thread's 4 cols
    float rq[4][4] = {};
    #pragma unroll
    for (int ni = 0; ni < 4; ++ni) {
        int col = c0 + ni * 16;
        float bv = bias[col];
        #pragma unroll
        for (int mi = 0; mi < 4; ++mi)
            #pragma unroll
            for (int r = 0; r < 4; ++r) {
                long row = tileM + r0 + mi * 16 + r;
                float v = (acc[mi][ni][r] + bv) + resid[row * H + col];
                vals[mi][ni][r] = v;
                rs[mi][r] += v;
                rq[mi][r] += v * v;
            }
    }
    // reduce across the 16-lane col group (lane&15); lane>>4 (rows) invariant
    #pragma unroll
    for (int mi = 0; mi < 4; ++mi)
        #pragma unroll
        for (int r = 0; r < 4; ++r) {
            float s = rs[mi][r], q = rq[mi][r];
            #pragma unroll
            for (int m = 1; m < 16; m <<= 1) {
                s += __shfl_xor(s, m, 64);
                q += __shfl_xor(q, m, 64);
            }
            rs[mi][r] = s; rq[mi][r] = q;
        }
    // exchange across the two wn halves via LDS (overlay dead As: 2KB of 8KB)
    float* sp = (float*)As;            // [2][128]
    float* sq = (float*)As + 256;      // [2][128]
    __syncthreads();                   // all frag reads of As retired
    if ((lane & 15) == 0) {
        #pragma unroll
        for (int mi = 0; mi < 4; ++mi)
            #pragma unroll
            for (int r = 0; r < 4; ++r) {
                int row = r0 + mi * 16 + r;      // 0..127 (covers wm-half)
                sp[wn * 128 + row] = rs[mi][r];
                sq[wn * 128 + row] = rq[mi][r];
            }
    }
    __syncthreads();
    #pragma unroll
    for (int mi = 0; mi < 4; ++mi)
        #pragma unroll
        for (int r = 0; r < 4; ++r) {
            int row = r0 + mi * 16 + r;
            float s = sp[row] + sp[128 + row];
            float q = sq[row] + sq[128 + row];
            float mean = s * (1.0f / H);
            float var  = q * (1.0f / H) - mean * mean;
            rs[mi][r] = mean;
            rq[mi][r] = rsqrtf(var + 1e-5f);
        }
    #pragma unroll
    for (int ni = 0; ni < 4; ++ni) {
        int col = c0 + ni * 16;
        float gv = g[col], bb = bvec[col];
        #pragma unroll
        for (int mi = 0; mi < 4; ++mi)
            #pragma unroll
            for (int r = 0; r < 4; ++r) {
                long row = tileM + r0 + mi * 16 + r;
                float o = (vals[mi][ni][r] - rs[mi][r]) * rq[mi][r] * gv + bb;
                out_bf[row * H + col] = f2b(o);
                if (WRITE_F32) out_f32[row * H + col] = o;
            }
    }
}

// ---------------------------------------------------------------------------
// prep: embed + pack_qkv + weight converts in ONE launch (block-range dispatch)
// [0,11008)      embed:    x = emb[inputs] + pos  (fp32 + bf16)
// [11008,11328)  pack_qkv: 6x[96,128] -> [640,128] bf16 + bias[640]
// [11328,11424)  Wproj 128x192 cvt
// [11424,12448)  Wff1  2048x128 cvt
// [12448,13472)  Wff2  128x2048 cvt
// [13472,17504)  Wfin  8000x128 cvt, zero-pad to 8064
// ---------------------------------------------------------------------------
__global__ __launch_bounds__(256) void prep_kernel(
    const int* __restrict__ inputs, const float* __restrict__ emb,
    const float* __restrict__ pos, float* __restrict__ xf, ushort* __restrict__ xb,
    const float* q1, const float* k1, const float* v1,
    const float* q2, const float* k2, const float* v2,
    const float* bq1, const float* bk1, const float* bv1,
    const float* bq2, const float* bk2, const float* bv2,
    ushort* __restrict__ Wqkv, float* __restrict__ bqkv,
    const float* __restrict__ Wproj, const float* __restrict__ Wff1,
    const float* __restrict__ Wff2,  const float* __restrict__ Wfin,
    ushort* __restrict__ Wp_b, ushort* __restrict__ W1_b,
    ushort* __restrict__ W2_b, ushort* __restrict__ Wf_b)
{
    const int b = blockIdx.x, tid = threadIdx.x;
    if (b < 11008) {
        long i = (long)b * 256 + tid;          // over NT*H
        int h  = (int)(i & 127);
        int nt = (int)(i >> 7);
        int t  = nt % T;
        float v = emb[(long)inputs[nt] * H + h] + pos[t * H + h];
        xf[i] = v;
        xb[i] = f2b(v);
    } else if (b < 11328) {
        int i = (b - 11008) * 256 + tid;       // 640*128
        int n = i >> 7, kk = i & 127;
        float val = 0.0f;
        if (n < 576) {
            const float* ws[6] = {q1, k1, v1, q2, k2, v2};
            val = ws[n / 96][(n % 96) * 128 + kk];
        }
        Wqkv[i] = f2b(val);
        if (kk == 0) {
            float bv = 0.0f;
            if (n < 576) {
                const float* bs[6] = {bq1, bk1, bv1, bq2, bk2, bv2};
                bv = bs[n / 96][n % 96];
            }
            bqkv[n] = bv;
        }
    } else if (b < 11424) {
        int i = (b - 11328) * 256 + tid;       // 128*192
        Wp_b[i] = f2b(Wproj[i]);
    } else if (b < 12448) {
        int i = (b - 11424) * 256 + tid;       // 2048*128
        W1_b[i] = f2b(Wff1[i]);
    } else if (b < 13472) {
        int i = (b - 12448) * 256 + tid;       // 128*2048
        W2_b[i] = f2b(Wff2[i]);
    } else {
        long i = (long)(b - 13472) * 256 + tid; // 8064*128
        long r = i >> 7;
        Wf_b[i] = f2b(r < OUTD ? Wfin[i] : 0.0f);
    }
}

// ---------------------------------------------------------------------------
// attention: one block per (head, batch). qkv fp32 [NT,576] layout
// [q1 k1 v1 q2 k2 v2] (96 each). writes h12 bf16 [NT,192].
// ---------------------------------------------------------------------------
__global__ __launch_bounds__(256) void attn_kernel(
    const float* __restrict__ qkv, ushort* __restrict__ h12)
{
    const int head = blockIdx.x;
    const int n    = blockIdx.y;
    const int tid  = threadIdx.x;
    __shared__ float q[T][DK], k[T][DK], v[T][DK];
    __shared__ float s[T][T + 1];
    const float scale = 0.10206207261596575f;   // 1/sqrt(96)
    const long base = (long)n * T * 576 + head * 288;

    for (int i = tid; i < T * DK; i += 256) {
        int r = i / DK, c = i % DK;
        q[r][c] = qkv[base + r * 576 + c];
        k[r][c] = qkv[base + r * 576 + 96 + c];
        v[r][c] = qkv[base + r * 576 + 192 + c];
    }
    __syncthreads();
    for (int i = tid; i < T * T; i += 256) {
        int r = i / T, c = i % T;
        float d = 0.0f;
        #pragma unroll 8
        for (int x = 0; x < DK; ++x) d += q[r][x] * k[c][x];
        s[r][c] = d * scale;
    }
    __syncthreads();
    if (tid < T) {
        float mx = -1e30f;
        for (int j = 0; j < T; ++j) mx = fmaxf(mx, s[tid][j]);
        float sum = 0.0f;
        for (int j = 0; j < T; ++j) { float e = __expf(s[tid][j] - mx); s[tid][j] = e; sum += e; }
        float inv = 1.0f / sum;
        for (int j = 0; j < T; ++j) s[tid][j] *= inv;
    }
    __syncthreads();
    for (int i = tid; i < T * DK; i += 256) {
        int r = i / DK, c = i % DK;
        float d = 0.0f;
        #pragma unroll
        for (int j = 0; j < T; ++j) d += s[r][j] * v[j][c];
        h12[((long)n * T + r) * 192 + head * 96 + c] = f2b(d);
    }
}

// ---------------------------------------------------------------------------
extern "C" void kernel_launch(void* const* d_in, const int* in_sizes, int n_in,
                              void* d_out, int out_size, void* d_ws, size_t ws_size,
                              hipStream_t stream)
{
    const int*   inputs  = (const int*)  d_in[0];
    const float* emb     = (const float*)d_in[1];
    const float* pos_emb = (const float*)d_in[2];
    const float* Wk1 = (const float*)d_in[3],  *bk1 = (const float*)d_in[4];
    const float* Wv1 = (const float*)d_in[5],  *bv1 = (const float*)d_in[6];
    const float* Wq1 = (const float*)d_in[7],  *bq1 = (const float*)d_in[8];
    const float* Wk2 = (const float*)d_in[9],  *bk2 = (const float*)d_in[10];
    const float* Wv2 = (const float*)d_in[11], *bv2 = (const float*)d_in[12];
    const float* Wq2 = (const float*)d_in[13], *bq2 = (const float*)d_in[14];
    const float* Wproj = (const float*)d_in[15], *bproj = (const float*)d_in[16];
    const float* g_mh  = (const float*)d_in[17], *b_mh  = (const float*)d_in[18];
    const float* Wff1  = (const float*)d_in[19], *bff1  = (const float*)d_in[20];
    const float* Wff2  = (const float*)d_in[21], *bff2  = (const float*)d_in[22];
    const float* g_ff  = (const float*)d_in[23], *b_ff  = (const float*)d_in[24];
    const float* Wfin  = (const float*)d_in[25], *bfin  = (const float*)d_in[26];

    // --- Scratch placement: dead-before-final-gemm buffers live in d_out ---
    char* scr = (char*)d_out;
    size_t soff = 0;
    auto salloc = [&](size_t bytes) {
        void* p = scr + soff;
        soff = (soff + bytes + 255) & ~(size_t)255;
        return p;
    };
    float*  x_f   = (float*) salloc((size_t)NT * H * 4);
    ushort* x_b   = (ushort*)salloc((size_t)NT * H * 2);
    float*  qkv   = (float*) salloc((size_t)NT * 576 * 4);
    ushort* h12   = (ushort*)salloc((size_t)NT * 192 * 2);
    float*  xln_f = (float*) salloc((size_t)NT * H * 4);
    ushort* xln_b = (ushort*)salloc((size_t)NT * H * 2);
    ushort* ffa   = (ushort*)salloc((size_t)NT * DFF * 2);
    ushort* Wqkv  = (ushort*)salloc(640 * 128 * 2);
    float*  bqkv  = (float*) salloc(640 * 4);
    ushort* Wp_b  = (ushort*)salloc(128 * 192 * 2);
    ushort* W1_b  = (ushort*)salloc((size_t)DFF * 128 * 2);
    ushort* W2_b  = (ushort*)salloc((size_t)128 * DFF * 2);
    // total ~182 MB << 704 MB

    char* ws = (char*)d_ws;
    size_t woff = 0;
    auto walloc = [&](size_t bytes) {
        void* p = ws + woff;
        woff = (woff + bytes + 255) & ~(size_t)255;
        return p;
    };
    ushort* y_b  = (ushort*)walloc((size_t)NT * H * 2);      // 5.6 MB
    ushort* Wf_b = (ushort*)walloc((size_t)8064 * 128 * 2);  // 2.1 MB

    const int MT = NT / 128;   // 172 M-tiles

    // 1. prep: embed + pack + all weight converts
    prep_kernel<<<17504, 256, 0, stream>>>(
        inputs, emb, pos_emb, x_f, x_b,
        Wq1, Wk1, Wv1, Wq2, Wk2, Wv2, bq1, bk1, bv1, bq2, bk2, bv2,
        Wqkv, bqkv, Wproj, Wff1, Wff2, Wfin, Wp_b, W1_b, W2_b, Wf_b);

    // 2. QKV projection: [NT,128] @ [640,128]^T -> [NT,576] fp32
    gemm_bt<false, false, false><<<dim3(5, MT), 256, 0, stream>>>(
        x_b, Wqkv, bqkv, qkv, NT, 576, 128);

    // 3. attention -> h12 bf16 [NT,192]
    attn_kernel<<<dim3(2, NB), 256, 0, stream>>>(qkv, h12);

    // 4. proj + LN1 fused: xln = LN(h12 @ Wp^T + bproj + x)
    gemm_ln<true><<<MT, 256, 0, stream>>>(
        h12, Wp_b, bproj, x_f, g_mh, b_mh, xln_b, xln_f, 192);

    // 5. FFN1 + relu -> bf16 [NT,2048]
    gemm_bt<true, true, false><<<dim3(16, MT), 256, 0, stream>>>(
        xln_b, W1_b, bff1, ffa, NT, DFF, 128);

    // 6. FFN2 + LN2 fused: y = LN(ffa @ W2^T + bff2 + xln)
    gemm_ln<false><<<MT, 256, 0, stream>>>(
        ffa, W2_b, bff2, xln_f, g_ff, b_ff, y_b, nullptr, DFF);

    // 7. final: [NT,128] @ [8064,128]^T -> d_out fp32 [NT,8000], NT stores
    gemm_bt<false, false, true><<<dim3(63, MT), 256, 0, stream>>>(
        y_b, Wf_b, bfin, (float*)d_out, NT, OUTD, 128);
}

// Round 4
// 974.075 us; speedup vs baseline: 1.1850x; 1.0607x over previous
//
#include <hip/hip_runtime.h>
#include <hip/hip_bf16.h>

typedef unsigned short ushort;
typedef __attribute__((ext_vector_type(4))) float floatx4;
typedef __attribute__((ext_vector_type(8))) short short8;

constexpr int NB   = 512;
constexpr int T    = 43;
constexpr int H    = 128;
constexpr int NT   = NB * T;       // 22016
constexpr int DK   = 96;
constexpr int DFF  = 2048;
constexpr int OUTD = 8000;

__device__ __forceinline__ ushort f2b(float f) {
    __hip_bfloat16 h = __float2bfloat16(f);
    return *reinterpret_cast<ushort*>(&h);
}

#define GLOAD16(g, l) __builtin_amdgcn_global_load_lds( \
    (const __attribute__((address_space(1))) unsigned int*)(g), \
    (__attribute__((address_space(3))) unsigned int*)(l), 16, 0, 0)

// ---------------------------------------------------------------------------
// GEMM: C[M,N] = A[M,K](bf16) @ B[Npad,K](bf16)^T + bias ; optional relu/bf16.
// Baseline single-buffer structure (16KB LDS, ~3-4 blocks/CU): these small-K
// GEMMs are latency-hidden by TLP across co-resident blocks — round-0's
// bigger-LDS variants cut occupancy and regressed (+92us). Do not re-add.
// NTS: non-temporal C store — ONLY for the final 704MB stream (never re-read),
// keeps y_b/Wf_b L2-resident. Never use NTS on a buffer a later kernel reads.
// ---------------------------------------------------------------------------
template<bool RELU, bool OUT_BF16, bool NTS>
__global__ __launch_bounds__(256) void gemm_bt(
    const ushort* __restrict__ A, const ushort* __restrict__ B,
    const float* __restrict__ bias, void* __restrict__ Cv,
    int M, int N, int K)
{
    __shared__ ushort As[128 * 32];
    __shared__ ushort Bs[128 * 32];
    const int tid  = threadIdx.x;
    const int lane = tid & 63;
    const int wm   = (tid >> 6) & 1;
    const int wn   = (tid >> 6) >> 1;
    const long tileM = (long)blockIdx.y * 128;
    const long tileN = (long)blockIdx.x * 128;

    floatx4 acc[4][4] = {};

    const ushort* ga0 = A + (tileM + (tid >> 2)) * (long)K + (tid & 3) * 8;
    const ushort* ga1 = A + (tileM + 64 + (tid >> 2)) * (long)K + (tid & 3) * 8;
    const ushort* gb0 = B + (tileN + (tid >> 2)) * (long)K + (tid & 3) * 8;
    const ushort* gb1 = B + (tileN + 64 + (tid >> 2)) * (long)K + (tid & 3) * 8;

    for (int k0 = 0; k0 < K; k0 += 32) {
        __syncthreads();
        GLOAD16(ga0 + k0, &As[tid * 8]);
        GLOAD16(ga1 + k0, &As[(tid + 256) * 8]);
        GLOAD16(gb0 + k0, &Bs[tid * 8]);
        GLOAD16(gb1 + k0, &Bs[(tid + 256) * 8]);
        __syncthreads();
        short8 af[4], bfr[4];
        #pragma unroll
        for (int mi = 0; mi < 4; ++mi)
            af[mi] = *(const short8*)&As[(wm * 64 + mi * 16 + (lane & 15)) * 32 + (lane >> 4) * 8];
        #pragma unroll
        for (int ni = 0; ni < 4; ++ni)
            bfr[ni] = *(const short8*)&Bs[(wn * 64 + ni * 16 + (lane & 15)) * 32 + (lane >> 4) * 8];
        #pragma unroll
        for (int mi = 0; mi < 4; ++mi)
            #pragma unroll
            for (int ni = 0; ni < 4; ++ni)
                acc[mi][ni] = __builtin_amdgcn_mfma_f32_16x16x32_bf16(
                    af[mi], bfr[ni], acc[mi][ni], 0, 0, 0);
    }

    const int r0 = wm * 64 + (lane >> 4) * 4;
    const int c0 = wn * 64 + (lane & 15);
    #pragma unroll
    for (int ni = 0; ni < 4; ++ni) {
        long col = tileN + c0 + ni * 16;
        if (col < N) {
            float bv = bias ? bias[col] : 0.0f;
            #pragma unroll
            for (int mi = 0; mi < 4; ++mi) {
                #pragma unroll
                for (int r = 0; r < 4; ++r) {
                    long row = tileM + r0 + mi * 16 + r;
                    float v = acc[mi][ni][r] + bv;
                    if (RELU) v = v > 0.0f ? v : 0.0f;
                    if (OUT_BF16) {
                        ushort hv = f2b(v);
                        ushort* p = (ushort*)Cv + row * N + col;
                        if (NTS) __builtin_nontemporal_store(hv, p); else *p = hv;
                    } else {
                        float* p = (float*)Cv + row * N + col;
                        if (NTS) __builtin_nontemporal_store(v, p); else *p = v;
                    }
                }
            }
        }
    }
}

// ---------------------------------------------------------------------------
// gemm_ln: C = A @ B^T + bias, then out = LN(C + resid) fused in the epilogue.
// N fixed = 128 (one block covers full rows -> in-block row statistics).
// Grid is 172 blocks = 0.67 blocks/CU: NO TLP to hide the per-k-step vmcnt
// drain, so THIS kernel (unlike gemm_bt) is double-buffered — occupancy
// cannot be hurt when there is <1 block/CU, and the drain hides under MFMA.
// ---------------------------------------------------------------------------
template<bool WRITE_F32>
__global__ __launch_bounds__(256) void gemm_ln(
    const ushort* __restrict__ A, const ushort* __restrict__ B,
    const float* __restrict__ bias, const float* __restrict__ resid,
    const float* __restrict__ g, const float* __restrict__ bvec,
    ushort* __restrict__ out_bf, float* __restrict__ out_f32, int K)
{
    __shared__ ushort As[2][128 * 32];
    __shared__ ushort Bs[2][128 * 32];
    const int tid  = threadIdx.x;
    const int lane = tid & 63;
    const int wm   = (tid >> 6) & 1;
    const int wn   = (tid >> 6) >> 1;
    const long tileM = (long)blockIdx.x * 128;

    floatx4 acc[4][4] = {};

    const ushort* ga0 = A + (tileM + (tid >> 2)) * (long)K + (tid & 3) * 8;
    const ushort* ga1 = A + (tileM + 64 + (tid >> 2)) * (long)K + (tid & 3) * 8;
    const ushort* gb0 = B + ((tid >> 2)) * (long)K + (tid & 3) * 8;
    const ushort* gb1 = B + (64 + (tid >> 2)) * (long)K + (tid & 3) * 8;

#define STAGE_LN(buf, k0) do { \
        GLOAD16(ga0 + (k0), &As[buf][tid * 8]); \
        GLOAD16(ga1 + (k0), &As[buf][(tid + 256) * 8]); \
        GLOAD16(gb0 + (k0), &Bs[buf][tid * 8]); \
        GLOAD16(gb1 + (k0), &Bs[buf][(tid + 256) * 8]); } while (0)

    const int nsteps = K >> 5;
    STAGE_LN(0, 0);
    int cur = 0;
    for (int t = 0; t < nsteps; ++t) {
        __syncthreads();                  // buf 'cur' ready (vmcnt drained)
        if (t + 1 < nsteps) STAGE_LN(cur ^ 1, (t + 1) * 32);
        short8 af[4], bfr[4];
        #pragma unroll
        for (int mi = 0; mi < 4; ++mi)
            af[mi] = *(const short8*)&As[cur][(wm * 64 + mi * 16 + (lane & 15)) * 32 + (lane >> 4) * 8];
        #pragma unroll
        for (int ni = 0; ni < 4; ++ni)
            bfr[ni] = *(const short8*)&Bs[cur][(wn * 64 + ni * 16 + (lane & 15)) * 32 + (lane >> 4) * 8];
        #pragma unroll
        for (int mi = 0; mi < 4; ++mi)
            #pragma unroll
            for (int ni = 0; ni < 4; ++ni)
                acc[mi][ni] = __builtin_amdgcn_mfma_f32_16x16x32_bf16(
                    af[mi], bfr[ni], acc[mi][ni], 0, 0, 0);
        cur ^= 1;
    }
#undef STAGE_LN

    // ---- epilogue: vals = acc + bias + resid; per-row mean/var; normalize
    const int r0 = wm * 64 + (lane >> 4) * 4;
    const int c0 = wn * 64 + (lane & 15);
    float vals[4][4][4];
    float rs[4][4] = {};   // per-(mi,r) partial sums over this thread's 4 cols
    float rq[4][4] = {};
    #pragma unroll
    for (int ni = 0; ni < 4; ++ni) {
        int col = c0 + ni * 16;
        float bv = bias[col];
        #pragma unroll
        for (int mi = 0; mi < 4; ++mi)
            #pragma unroll
            for (int r = 0; r < 4; ++r) {
                long row = tileM + r0 + mi * 16 + r;
                float v = (acc[mi][ni][r] + bv) + resid[row * H + col];
                vals[mi][ni][r] = v;
                rs[mi][r] += v;
                rq[mi][r] += v * v;
            }
    }
    // reduce across the 16-lane col group (lane&15); lane>>4 (rows) invariant
    #pragma unroll
    for (int mi = 0; mi < 4; ++mi)
        #pragma unroll
        for (int r = 0; r < 4; ++r) {
            float s = rs[mi][r], q = rq[mi][r];
            #pragma unroll
            for (int m = 1; m < 16; m <<= 1) {
                s += __shfl_xor(s, m, 64);
                q += __shfl_xor(q, m, 64);
            }
            rs[mi][r] = s; rq[mi][r] = q;
        }
    // exchange across the two wn halves via LDS (overlay dead As buffer)
    float* sp = (float*)As;            // [2][128]
    float* sq = (float*)As + 256;      // [2][128]
    __syncthreads();                   // all frag reads of As retired
    if ((lane & 15) == 0) {
        #pragma unroll
        for (int mi = 0; mi < 4; ++mi)
            #pragma unroll
            for (int r = 0; r < 4; ++r) {
                int row = r0 + mi * 16 + r;      // 0..127 (covers wm-half)
                sp[wn * 128 + row] = rs[mi][r];
                sq[wn * 128 + row] = rq[mi][r];
            }
    }
    __syncthreads();
    #pragma unroll
    for (int mi = 0; mi < 4; ++mi)
        #pragma unroll
        for (int r = 0; r < 4; ++r) {
            int row = r0 + mi * 16 + r;
            float s = sp[row] + sp[128 + row];
            float q = sq[row] + sq[128 + row];
            float mean = s * (1.0f / H);
            float var  = q * (1.0f / H) - mean * mean;
            rs[mi][r] = mean;
            rq[mi][r] = rsqrtf(var + 1e-5f);
        }
    #pragma unroll
    for (int ni = 0; ni < 4; ++ni) {
        int col = c0 + ni * 16;
        float gv = g[col], bb = bvec[col];
        #pragma unroll
        for (int mi = 0; mi < 4; ++mi)
            #pragma unroll
            for (int r = 0; r < 4; ++r) {
                long row = tileM + r0 + mi * 16 + r;
                float o = (vals[mi][ni][r] - rs[mi][r]) * rq[mi][r] * gv + bb;
                out_bf[row * H + col] = f2b(o);
                if (WRITE_F32) out_f32[row * H + col] = o;
            }
    }
}

// ---------------------------------------------------------------------------
// prep: embed + pack_qkv + weight converts in ONE launch (block-range dispatch)
// ---------------------------------------------------------------------------
__global__ __launch_bounds__(256) void prep_kernel(
    const int* __restrict__ inputs, const float* __restrict__ emb,
    const float* __restrict__ pos, float* __restrict__ xf, ushort* __restrict__ xb,
    const float* q1, const float* k1, const float* v1,
    const float* q2, const float* k2, const float* v2,
    const float* bq1, const float* bk1, const float* bv1,
    const float* bq2, const float* bk2, const float* bv2,
    ushort* __restrict__ Wqkv, float* __restrict__ bqkv,
    const float* __restrict__ Wproj, const float* __restrict__ Wff1,
    const float* __restrict__ Wff2,  const float* __restrict__ Wfin,
    ushort* __restrict__ Wp_b, ushort* __restrict__ W1_b,
    ushort* __restrict__ W2_b, ushort* __restrict__ Wf_b)
{
    const int b = blockIdx.x, tid = threadIdx.x;
    if (b < 11008) {
        long i = (long)b * 256 + tid;          // over NT*H
        int h  = (int)(i & 127);
        int nt = (int)(i >> 7);
        int t  = nt % T;
        float v = emb[(long)inputs[nt] * H + h] + pos[t * H + h];
        xf[i] = v;
        xb[i] = f2b(v);
    } else if (b < 11328) {
        int i = (b - 11008) * 256 + tid;       // 640*128
        int n = i >> 7, kk = i & 127;
        float val = 0.0f;
        if (n < 576) {
            const float* ws[6] = {q1, k1, v1, q2, k2, v2};
            val = ws[n / 96][(n % 96) * 128 + kk];
        }
        Wqkv[i] = f2b(val);
        if (kk == 0) {
            float bv = 0.0f;
            if (n < 576) {
                const float* bs[6] = {bq1, bk1, bv1, bq2, bk2, bv2};
                bv = bs[n / 96][n % 96];
            }
            bqkv[n] = bv;
        }
    } else if (b < 11424) {
        int i = (b - 11328) * 256 + tid;       // 128*192
        Wp_b[i] = f2b(Wproj[i]);
    } else if (b < 12448) {
        int i = (b - 11424) * 256 + tid;       // 2048*128
        W1_b[i] = f2b(Wff1[i]);
    } else if (b < 13472) {
        int i = (b - 12448) * 256 + tid;       // 128*2048
        W2_b[i] = f2b(Wff2[i]);
    } else {
        long i = (long)(b - 13472) * 256 + tid; // 8064*128
        long r = i >> 7;
        Wf_b[i] = f2b(r < OUTD ? Wfin[i] : 0.0f);
    }
}

// ---------------------------------------------------------------------------
// attention: one block per (head, batch). qkv fp32 [NT,576] layout
// [q1 k1 v1 q2 k2 v2] (96 each). writes h12 bf16 [NT,192].
// LDS PAD = DK+1 = 97: DK=96 is 0 mod 32, so the QK^T read k[c][x]
// (c per-lane, x uniform) put all ~43 lanes in ONE bank (43-way conflict,
// ~15x serialization on half the inner-loop LDS traffic — the hidden whale).
// 97 mod 32 = 1 -> consecutive c hits consecutive banks -> conflict-free.
// ---------------------------------------------------------------------------
constexpr int DKP = DK + 1;   // 97
__global__ __launch_bounds__(256) void attn_kernel(
    const float* __restrict__ qkv, ushort* __restrict__ h12)
{
    const int head = blockIdx.x;
    const int n    = blockIdx.y;
    const int tid  = threadIdx.x;
    __shared__ float q[T][DKP], k[T][DKP], v[T][DKP];
    __shared__ float s[T][T + 1];
    const float scale = 0.10206207261596575f;   // 1/sqrt(96)
    const long base = (long)n * T * 576 + head * 288;

    for (int i = tid; i < T * DK; i += 256) {
        int r = i / DK, c = i % DK;
        q[r][c] = qkv[base + r * 576 + c];
        k[r][c] = qkv[base + r * 576 + 96 + c];
        v[r][c] = qkv[base + r * 576 + 192 + c];
    }
    __syncthreads();
    for (int i = tid; i < T * T; i += 256) {
        int r = i / T, c = i % T;
        float d = 0.0f;
        #pragma unroll 8
        for (int x = 0; x < DK; ++x) d += q[r][x] * k[c][x];
        s[r][c] = d * scale;
    }
    __syncthreads();
    if (tid < T) {
        float mx = -1e30f;
        for (int j = 0; j < T; ++j) mx = fmaxf(mx, s[tid][j]);
        float sum = 0.0f;
        for (int j = 0; j < T; ++j) { float e = __expf(s[tid][j] - mx); s[tid][j] = e; sum += e; }
        float inv = 1.0f / sum;
        for (int j = 0; j < T; ++j) s[tid][j] *= inv;
    }
    __syncthreads();
    for (int i = tid; i < T * DK; i += 256) {
        int r = i / DK, c = i % DK;
        float d = 0.0f;
        #pragma unroll
        for (int j = 0; j < T; ++j) d += s[r][j] * v[j][c];
        h12[((long)n * T + r) * 192 + head * 96 + c] = f2b(d);
    }
}

// ---------------------------------------------------------------------------
extern "C" void kernel_launch(void* const* d_in, const int* in_sizes, int n_in,
                              void* d_out, int out_size, void* d_ws, size_t ws_size,
                              hipStream_t stream)
{
    const int*   inputs  = (const int*)  d_in[0];
    const float* emb     = (const float*)d_in[1];
    const float* pos_emb = (const float*)d_in[2];
    const float* Wk1 = (const float*)d_in[3],  *bk1 = (const float*)d_in[4];
    const float* Wv1 = (const float*)d_in[5],  *bv1 = (const float*)d_in[6];
    const float* Wq1 = (const float*)d_in[7],  *bq1 = (const float*)d_in[8];
    const float* Wk2 = (const float*)d_in[9],  *bk2 = (const float*)d_in[10];
    const float* Wv2 = (const float*)d_in[11], *bv2 = (const float*)d_in[12];
    const float* Wq2 = (const float*)d_in[13], *bq2 = (const float*)d_in[14];
    const float* Wproj = (const float*)d_in[15], *bproj = (const float*)d_in[16];
    const float* g_mh  = (const float*)d_in[17], *b_mh  = (const float*)d_in[18];
    const float* Wff1  = (const float*)d_in[19], *bff1  = (const float*)d_in[20];
    const float* Wff2  = (const float*)d_in[21], *bff2  = (const float*)d_in[22];
    const float* g_ff  = (const float*)d_in[23], *b_ff  = (const float*)d_in[24];
    const float* Wfin  = (const float*)d_in[25], *bfin  = (const float*)d_in[26];

    // --- Scratch placement: dead-before-final-gemm buffers live in d_out ---
    char* scr = (char*)d_out;
    size_t soff = 0;
    auto salloc = [&](size_t bytes) {
        void* p = scr + soff;
        soff = (soff + bytes + 255) & ~(size_t)255;
        return p;
    };
    float*  x_f   = (float*) salloc((size_t)NT * H * 4);
    ushort* x_b   = (ushort*)salloc((size_t)NT * H * 2);
    float*  qkv   = (float*) salloc((size_t)NT * 576 * 4);
    ushort* h12   = (ushort*)salloc((size_t)NT * 192 * 2);
    float*  xln_f = (float*) salloc((size_t)NT * H * 4);
    ushort* xln_b = (ushort*)salloc((size_t)NT * H * 2);
    ushort* ffa   = (ushort*)salloc((size_t)NT * DFF * 2);
    ushort* Wqkv  = (ushort*)salloc(640 * 128 * 2);
    float*  bqkv  = (float*) salloc(640 * 4);
    ushort* Wp_b  = (ushort*)salloc(128 * 192 * 2);
    ushort* W1_b  = (ushort*)salloc((size_t)DFF * 128 * 2);
    ushort* W2_b  = (ushort*)salloc((size_t)128 * DFF * 2);
    // total ~182 MB << 704 MB

    char* ws = (char*)d_ws;
    size_t woff = 0;
    auto walloc = [&](size_t bytes) {
        void* p = ws + woff;
        woff = (woff + bytes + 255) & ~(size_t)255;
        return p;
    };
    ushort* y_b  = (ushort*)walloc((size_t)NT * H * 2);      // 5.6 MB
    ushort* Wf_b = (ushort*)walloc((size_t)8064 * 128 * 2);  // 2.1 MB

    const int MT = NT / 128;   // 172 M-tiles

    // 1. prep: embed + pack + all weight converts
    prep_kernel<<<17504, 256, 0, stream>>>(
        inputs, emb, pos_emb, x_f, x_b,
        Wq1, Wk1, Wv1, Wq2, Wk2, Wv2, bq1, bk1, bv1, bq2, bk2, bv2,
        Wqkv, bqkv, Wproj, Wff1, Wff2, Wfin, Wp_b, W1_b, W2_b, Wf_b);

    // 2. QKV projection: [NT,128] @ [640,128]^T -> [NT,576] fp32
    gemm_bt<false, false, false><<<dim3(5, MT), 256, 0, stream>>>(
        x_b, Wqkv, bqkv, qkv, NT, 576, 128);

    // 3. attention -> h12 bf16 [NT,192]
    attn_kernel<<<dim3(2, NB), 256, 0, stream>>>(qkv, h12);

    // 4. proj + LN1 fused: xln = LN(h12 @ Wp^T + bproj + x)
    gemm_ln<true><<<MT, 256, 0, stream>>>(
        h12, Wp_b, bproj, x_f, g_mh, b_mh, xln_b, xln_f, 192);

    // 5. FFN1 + relu -> bf16 [NT,2048]
    gemm_bt<true, true, false><<<dim3(16, MT), 256, 0, stream>>>(
        xln_b, W1_b, bff1, ffa, NT, DFF, 128);

    // 6. FFN2 + LN2 fused: y = LN(ffa @ W2^T + bff2 + xln)
    gemm_ln<false><<<MT, 256, 0, stream>>>(
        ffa, W2_b, bff2, xln_f, g_ff, b_ff, y_b, nullptr, DFF);

    // 7. final: [NT,128] @ [8064,128]^T -> d_out fp32 [NT,8000], NT stores
    gemm_bt<false, false, true><<<dim3(63, MT), 256, 0, stream>>>(
        y_b, Wf_b, bfin, (float*)d_out, NT, OUTD, 128);
}